// Round 14
// baseline (52.898 us; speedup 1.0000x reference)
//
#include <hip/hip_runtime.h>

#define BB 32
#define NN 1024
#define MM 1024
#define DD 128

typedef __attribute__((ext_vector_type(4))) float f32x4;
typedef __attribute__((ext_vector_type(8))) __bf16 bf16x8;
typedef unsigned short ushort_t;
typedef unsigned int uint_t;

#define L2E 1.44269504f
#define KEXP 9.357623e-14f      // exp(-30): folded softmax shift
#define KEXPINV 1.0686475e13f   // exp(+30)

__device__ __forceinline__ unsigned f2bf(float x) {
    unsigned u = __builtin_bit_cast(unsigned, x);
    return (u + 0x7fffu + ((u >> 16) & 1u)) >> 16;  // RNE bf16, finite inputs
}

// async global->LDS, 16 B per lane; dest must be linear (base + lane*16)
#define GLOAD16(gp, lp)                                                     \
    __builtin_amdgcn_global_load_lds(                                       \
        (const __attribute__((address_space(1))) unsigned int*)(gp),        \
        (__attribute__((address_space(3))) unsigned int*)(lp), 16, 0, 0)

// ---- Kernel 1 (prep): gq = bf16(g)^T tiles ; e2 = g·a2 ; e1 = h·a1 ----------
__global__ __launch_bounds__(256) void prep(
    const float* __restrict__ g, const float* __restrict__ h,
    const float* __restrict__ a1, const float* __restrict__ a2,
    ushort_t* __restrict__ gq, float* __restrict__ e1, float* __restrict__ e2)
{
    __shared__ ushort_t tl[DD][66];  // +2 pad breaks write bank conflicts
    int b = blockIdx.y, m0 = blockIdx.x * 64, t = threadIdx.x;

    #pragma unroll
    for (int i = 0; i < 8; i++) {
        int idx = i * 256 + t;
        int m = idx >> 5;            // 32 consecutive lanes share row m
        int c4 = (idx & 31) * 4;
        float4 v = *(const float4*)(h + ((size_t)(b * NN + m0 + m)) * DD + c4);
        float4 av = *(const float4*)(a1 + c4);
        float p = v.x * av.x + v.y * av.y + v.z * av.z + v.w * av.w;
        #pragma unroll
        for (int s = 16; s; s >>= 1) p += __shfl_xor(p, s);
        if ((t & 31) == 0) e1[b * NN + m0 + m] = p;
    }
    #pragma unroll
    for (int i = 0; i < 8; i++) {
        int idx = i * 256 + t;
        int m = idx >> 5;
        int c4 = (idx & 31) * 4;
        float4 v = *(const float4*)(g + ((size_t)(b * MM + m0 + m)) * DD + c4);
        tl[c4 + 0][m] = (ushort_t)f2bf(v.x);
        tl[c4 + 1][m] = (ushort_t)f2bf(v.y);
        tl[c4 + 2][m] = (ushort_t)f2bf(v.z);
        tl[c4 + 3][m] = (ushort_t)f2bf(v.w);
        float4 av = *(const float4*)(a2 + c4);
        float p = v.x * av.x + v.y * av.y + v.z * av.z + v.w * av.w;
        #pragma unroll
        for (int s = 16; s; s >>= 1) p += __shfl_xor(p, s);
        if ((t & 31) == 0) e2[b * MM + m0 + m] = p;
    }
    __syncthreads();
    #pragma unroll
    for (int i = 0; i < 4; i++) {
        int idx = i * 256 + t;
        int d = idx >> 3;            // 0..127
        int c = (idx & 7) * 8;       // local m group
        int4 o;
        o.x = (int)((unsigned)tl[d][c + 0] | ((unsigned)tl[d][c + 1] << 16));
        o.y = (int)((unsigned)tl[d][c + 2] | ((unsigned)tl[d][c + 3] << 16));
        o.z = (int)((unsigned)tl[d][c + 4] | ((unsigned)tl[d][c + 5] << 16));
        o.w = (int)((unsigned)tl[d][c + 6] | ((unsigned)tl[d][c + 7] << 16));
        int mg = m0 + c;
        *(int4*)(gq + (((size_t)((b * 32 + (mg >> 5)) * DD + d)) << 5) + (mg & 31)) = o;
    }
}

// ---- Kernel 2: fused adj+softmax+PV, ring-3 LDS, 4 blocks/CU ----------------
// block = 32 rows x 128 d, 4 waves: wave (wr,wd) = 16 rows x 64 d (softmax
// duplicated across wd). grid 1024 = 4 blocks/CU = 16 waves/CU.
// Per chunk: vmcnt(3) [stage k landed] -> raw s_barrier -> STAGE(k+2) ->
// COMPUTE(k). 2 stages in flight; buffer (k+2)%3 last read at COMPUTE(k-1).
__global__ __launch_bounds__(256, 4) void attn_tiled(
    const int* __restrict__ adj, const ushort_t* __restrict__ gq,
    const float* __restrict__ e1, const float* __restrict__ e2,
    float* __restrict__ out)
{
    __shared__ __align__(16) float e2S[MM];             // 4 KB
    __shared__ __align__(16) int adjS[3][32 * 32];      // 3 x 4 KB
    __shared__ __align__(16) ushort_t gqS[3][128 * 32]; // 3 x 8 KB

    int b = blockIdx.y, n0 = blockIdx.x * 32, t = threadIdx.x;
    int wid = t >> 6, lane = t & 63;
    int wr = wid >> 1, wd = wid & 1;
    int rlo = lane & 15, hh = lane >> 4;
    int r = wr * 16 + rlo;           // block-local row 0..31
    int r8 = r & 7;

    // stage e2 (scaled to log2 domain)
    {
        float4 ev = *(const float4*)(e2 + b * MM + t * 4);
        ev.x *= L2E; ev.y *= L2E; ev.z *= L2E; ev.w *= L2E;
        *(float4*)(&e2S[t * 4]) = ev;
    }
    float e1f = L2E * e1[b * NN + n0 + r];
    __syncthreads();                 // e2S ready (no DMA in flight yet)

    const int* adjb = adj + (size_t)(b * NN + n0) * MM;
    const ushort_t* gqb = gq + (size_t)b * (32 * DD * 32);

    // adj staging: 256 x 16B slots = 32 rows x 8 slots, src-swizzled
    int arow = t >> 3, aseg = (t & 7) ^ (arow & 7);
    // gq staging: 512 slots = 128 d-rows x 4 slots of 8 shorts, src-swizzled
    int di0 = t, di1 = t + 256;
    int gd0 = di0 >> 2, gseg0 = (di0 & 3) ^ ((gd0 >> 1) & 3);
    int gd1 = di1 >> 2, gseg1 = (di1 & 3) ^ ((gd1 >> 1) & 3);

#define STAGE(P, K) do {                                                    \
        GLOAD16(adjb + (size_t)arow * MM + (K) * 32 + aseg * 4,             \
                &adjS[P][t * 4]);                                           \
        GLOAD16(gqb + (size_t)(K) * 4096 + gd0 * 32 + gseg0 * 8,            \
                &gqS[P][di0 * 8]);                                          \
        GLOAD16(gqb + (size_t)(K) * 4096 + gd1 * 32 + gseg1 * 8,            \
                &gqS[P][di1 * 8]);                                          \
    } while (0)

    f32x4 acc[4];
    #pragma unroll
    for (int j = 0; j < 4; j++) acc[j] = (f32x4){0.f, 0.f, 0.f, 0.f};
    float zl = 0.f, dl = 0.f;

#define COMPUTE(P, K) do {                                                  \
        int4 a0 = *(const int4*)(&adjS[P][r * 32 + ((2 * hh) ^ r8) * 4]);   \
        int4 a1 = *(const int4*)(&adjS[P][r * 32 + ((2 * hh + 1) ^ r8) * 4]);\
        float4 ev0 = *(const float4*)(&e2S[(K) * 32 + 8 * hh]);             \
        float4 ev1 = *(const float4*)(&e2S[(K) * 32 + 8 * hh + 4]);         \
        float ex[8] = {ev0.x, ev0.y, ev0.z, ev0.w,                          \
                       ev1.x, ev1.y, ev1.z, ev1.w};                         \
        int   ax[8] = {a0.x, a0.y, a0.z, a0.w, a1.x, a1.y, a1.z, a1.w};     \
        bf16x8 af;                                                          \
        _Pragma("unroll")                                                   \
        for (int jj = 0; jj < 8; jj++) {                                    \
            float sp = e1f + ex[jj];                                        \
            float lk = fmaxf(sp, 0.2f * sp);                                \
            float sel = (ax[jj] > 0) ? KEXP : 0.f;                          \
            float wv = sel * __builtin_amdgcn_exp2f(lk);                    \
            zl += wv;                                                       \
            dl += sel;                                                      \
            af[jj] = (__bf16)wv;                                            \
        }                                                                   \
        _Pragma("unroll")                                                   \
        for (int j = 0; j < 4; j++) {                                       \
            int d = wd * 64 + j * 16 + rlo;                                 \
            int4 bv = *(const int4*)(                                       \
                &gqS[P][d * 32 + (hh ^ ((rlo >> 1) & 3)) * 8]);             \
            acc[j] = __builtin_amdgcn_mfma_f32_16x16x32_bf16(               \
                         af, __builtin_bit_cast(bf16x8, bv), acc[j], 0,0,0);\
        }                                                                   \
    } while (0)

    // prologue: 2 stages in flight (6 DMA ops/thread)
    STAGE(0, 0); STAGE(1, 1);

    int pk = 0, p2 = 2;
    for (int k = 0; k < 31; ++k) {
        asm volatile("s_waitcnt vmcnt(3)" ::: "memory");  // stage k landed
        __builtin_amdgcn_s_barrier();                     // raw: no drain
        __builtin_amdgcn_sched_barrier(0);
        if (k < 30) STAGE(p2, k + 2);                     // overwrites (k-1)%3
        COMPUTE(pk, k);
        pk = (pk == 2) ? 0 : pk + 1;
        p2 = (p2 == 2) ? 0 : p2 + 1;
    }
    asm volatile("s_waitcnt vmcnt(0)" ::: "memory");      // stage 31 landed
    __builtin_amdgcn_s_barrier();
    __builtin_amdgcn_sched_barrier(0);
    COMPUTE(pk, 31);

#undef COMPUTE
#undef STAGE

    // per-row Z, deg: lanes sharing rlo hold partials -> reduce lane bits 4,5
    zl += __shfl_xor(zl, 16); zl += __shfl_xor(zl, 32);
    dl += __shfl_xor(dl, 16); dl += __shfl_xor(dl, 32);
    float sc = (dl > 0.f) ? (dl * KEXPINV) / zl : 0.f;   // = deg / Z

    float scr[4];
    #pragma unroll
    for (int rg = 0; rg < 4; rg++) scr[rg] = __shfl(sc, 4 * hh + rg);

    // C layout: col = rlo, row(within frag) = 4*hh + rg
    float* ob = out + ((size_t)(b * NN + n0 + wr * 16)) * DD + wd * 64 + rlo;
    #pragma unroll
    for (int j = 0; j < 4; j++)
        #pragma unroll
        for (int rg = 0; rg < 4; rg++)
            ob[(size_t)(4 * hh + rg) * DD + j * 16] = acc[j][rg] * scr[rg];
}

extern "C" void kernel_launch(void* const* d_in, const int* in_sizes, int n_in,
                              void* d_out, int out_size, void* d_ws, size_t ws_size,
                              hipStream_t stream) {
    const float* h   = (const float*)d_in[0];
    const float* g   = (const float*)d_in[1];
    const int*   adj = (const int*)d_in[2];
    const float* a1  = (const float*)d_in[3];
    const float* a2  = (const float*)d_in[4];
    float* out = (float*)d_out;

    // workspace: e1 @0 (128 KB), e2 @128 KB (128 KB), gq @512 KB (8 MB)
    char* ws = (char*)d_ws;
    float*    e1 = (float*)(ws);
    float*    e2 = (float*)(ws + (128u << 10));
    ushort_t* gq = (ushort_t*)(ws + (512u << 10));

    prep<<<dim3(MM / 64, BB), 256, 0, stream>>>(g, h, a1, a2, gq, e1, e2);
    attn_tiled<<<dim3(NN / 32, BB), 256, 0, stream>>>(adj, gq, e1, e2, out);
}